// Round 8
// baseline (168.307 us; speedup 1.0000x reference)
//
#include <hip/hip_runtime.h>

typedef _Float16 half4  __attribute__((ext_vector_type(4)));
typedef _Float16 half8  __attribute__((ext_vector_type(8)));
typedef float    f32x4  __attribute__((ext_vector_type(4)));

#define EC 768      // per-wave LDS edge-index capacity for layer-1 chain-break
#define CAP 4096    // bucket capacity (edges); E/NBUCK ~ 3061, ~17 sigma margin
#define CHUNK 2048  // edges per pass-A block (8 per thread, int4-vectorized)
#define CPAD 16     // cur[] stride in ints: one counter per 64B line (atomic decontention)
#define GA_PER 4    // gather units per edge block in pass A (rest ride pass B)

// ---------------- emb gather role: one half8 chunk per (unit,lane) ----------------
__device__ __forceinline__ void gather_unit(const int* __restrict__ ent,
                                            const float* __restrict__ emb,
                                            _Float16* __restrict__ X,
                                            int unit, int lt, int N) {
  int t = unit * 256 + lt;
  if (t >= N * 16) return;
  int node = t >> 4, g = t & 15;
  const float4* s = (const float4*)(emb + (long)ent[node] * 128 + g * 8);
  float4 a = s[0], c = s[1];
  half8 o;
  o[0] = (_Float16)a.x; o[1] = (_Float16)a.y; o[2] = (_Float16)a.z; o[3] = (_Float16)a.w;
  o[4] = (_Float16)c.x; o[5] = (_Float16)c.y; o[6] = (_Float16)c.z; o[7] = (_Float16)c.w;
  *(half8*)(X + (long)t * 8) = o;
}

// B-frag order: lane holds B[kt*32+(lane>>4)*8+j][nt*16+(lane&15)], j=0..7.
__device__ __forceinline__ void pack_dev(const float* Wa, const float* Wb,
                                         _Float16* out, int NT, int ncols, int t) {
  int lane = t & 63, tile = t >> 6;
  int nt = tile % NT, kt = tile / NT;
  int n  = nt * 16 + (lane & 15);
  int kb = kt * 32 + (lane >> 4) * 8;
  half8 o;
#pragma unroll
  for (int j = 0; j < 8; ++j) {
    int k = kb + j;
    float w = (k < 128) ? Wa[k * ncols + n] : Wb[(k - 128) * ncols + n];
    o[j] = (_Float16)w;
  }
  *(half8*)(out + (long)t * 8) = o;
}

// ---------------- pass A: LDS-histogram bucket scatter ∥ partial gather ∥ packs ---
// Edges binned by dst>>8 into fixed CAP regions. Per (block,bin) ONE global atomic
// (space allocation, line-padded counters); per-edge rank from LDS histogram return.
// Packed word: (src<<8)|(dst&255) — 4 B/edge (requires N < 2^23).
__global__ __launch_bounds__(256) void bucketA_k(
    const int* __restrict__ src, const int* __restrict__ dst,
    int* __restrict__ cur, int* __restrict__ buck,
    const int* __restrict__ ent, const float* __restrict__ emb, _Float16* __restrict__ X,
    const float* __restrict__ W1l, const float* __restrict__ W1r, _Float16* __restrict__ Wp1,
    const float* __restrict__ W2l, const float* __restrict__ W2r, const float* __restrict__ Wc,
    _Float16* __restrict__ Wz, const float* __restrict__ b2, const float* __restrict__ bc,
    float* __restrict__ bpr, int N, int E, int NA, int NBUCK, int IBA) {
  int b = blockIdx.x;
  if (b < IBA) {
    int grp = b / (GA_PER + 1), ph = b % (GA_PER + 1);
    if (ph != 0) { gather_unit(ent, emb, X, grp * GA_PER + ph - 1, threadIdx.x, N); return; }
    __shared__ int lbin[256], gbase[256];
    int tl = threadIdx.x;
    lbin[tl] = 0; __syncthreads();
    int e0 = grp * CHUNK;
    int pk[8], bn[8], lr[8];
    if (e0 + CHUNK <= E) {                         // full block: int4-vectorized
      const int4* dp = (const int4*)(dst + e0 + tl * 8);
      const int4* sp = (const int4*)(src + e0 + tl * 8);
      int4 d0 = dp[0], d1 = dp[1], s0 = sp[0], s1 = sp[1];
      int dv[8] = {d0.x, d0.y, d0.z, d0.w, d1.x, d1.y, d1.z, d1.w};
      int sv[8] = {s0.x, s0.y, s0.z, s0.w, s1.x, s1.y, s1.z, s1.w};
#pragma unroll
      for (int k = 0; k < 8; ++k) {
        bn[k] = dv[k] >> 8;
        pk[k] = (sv[k] << 8) | (dv[k] & 255);
        lr[k] = atomicAdd(&lbin[bn[k]], 1);
      }
    } else {                                       // tail block: scalar guarded
#pragma unroll
      for (int k = 0; k < 8; ++k) {
        int e = e0 + tl * 8 + k;
        bn[k] = -1;
        if (e < E) {
          int d = dst[e];
          bn[k] = d >> 8;
          pk[k] = (src[e] << 8) | (d & 255);
          lr[k] = atomicAdd(&lbin[bn[k]], 1);
        }
      }
    }
    __syncthreads();
    gbase[tl] = (tl < NBUCK && lbin[tl]) ? atomicAdd(&cur[tl * CPAD], lbin[tl]) : 0;
    __syncthreads();
#pragma unroll
    for (int k = 0; k < 8; ++k) {
      if (bn[k] >= 0) {
        int idx = gbase[bn[k]] + lr[k];
        if (idx < CAP) buck[(long)bn[k] * CAP + idx] = pk[k];
      }
    }
  } else if (b < IBA + 16) {                       // W1 concat pack (KT=8, NT=8)
    pack_dev(W1l, W1r, Wp1, 8, 128, (b - IBA) * 256 + threadIdx.x);
  } else if (b < IBA + 32) {                       // Wz fold: one elem/thread
    int i = (b - IBA - 16) * 256 + threadIdx.x;    // packed element index, 4096 total
    int j = i & 7, lane = (i >> 3) & 63, tile = i >> 9;
    int nt = tile & 1, kt = tile >> 1;
    int k = kt * 32 + (lane >> 4) * 8 + j;
    int c = lane & 15;
    const float* W = nt ? W2r : W2l;
    float s = 0.f;
#pragma unroll 8
    for (int q = 0; q < 128; ++q) s += W[k * 128 + q] * Wc[q * 16 + c];
    Wz[i] = (_Float16)s;
  } else {                                         // b' = b2@Wc + bc
    int n = threadIdx.x;
    if (n < 16) {
      float s = bc[n];
      for (int k = 0; k < 128; ++k) s += b2[k] * Wc[k * 16 + n];
      bpr[n] = s;
    }
  }
}

// ---------------- pass B: per-bucket degree+scan+rank ∥ remaining emb gather ------
// One 512-thread block per bucket (256 nodes); gather-ballast blocks (2 units each)
// fill the machine. bucketB needs only buck/cur — no X dependency.
__global__ __launch_bounds__(512) void bucketB_k(
    const int* __restrict__ cur, const int* __restrict__ buck,
    int* __restrict__ row_off, int* __restrict__ csr,
    const int* __restrict__ ent, const float* __restrict__ emb,
    _Float16* __restrict__ X, int goff, int N, int E, int NBUCK) {
  int B0 = blockIdx.x, tl = threadIdx.x;
  if (B0 >= NBUCK) {                               // gather role: 2 units per block
    int unit = goff + (B0 - NBUCK) * 2 + (tl >> 8);
    gather_unit(ent, emb, X, unit, tl & 255, N);
    return;
  }
  __shared__ int sA[256], cnt[256], sB[256], run[256];
  // exclusive prefix of bucket sizes -> this bucket's global edge base
  if (tl < 256) sA[tl] = (tl < NBUCK) ? cur[tl * CPAD] : 0;
  if (tl < 256) cnt[tl] = 0;
  __syncthreads();
  for (int off = 1; off < 256; off <<= 1) {
    int a = (tl < 256) ? sA[tl] : 0;
    int bb = (tl >= off && tl < 256) ? sA[tl - off] : 0;
    __syncthreads();
    if (tl < 256) sA[tl] = a + bb;
    __syncthreads();
  }
  int bsz = cur[B0 * CPAD]; if (bsz > CAP) bsz = CAP;
  int ebase = sA[B0] - bsz;
  // per-node counts (LDS atomics)
  const int* bp = buck + (long)B0 * CAP;
  for (int i = tl; i < bsz; i += 512) atomicAdd(&cnt[bp[i] & 255], 1);
  __syncthreads();
  // exclusive scan -> local row offsets
  int cv = (tl < 256) ? cnt[tl] : 0;
  if (tl < 256) sB[tl] = cv;
  __syncthreads();
  for (int off = 1; off < 256; off <<= 1) {
    int a = (tl < 256) ? sB[tl] : 0;
    int bb = (tl >= off && tl < 256) ? sB[tl - off] : 0;
    __syncthreads();
    if (tl < 256) sB[tl] = a + bb;
    __syncthreads();
  }
  if (tl < 256) {
    int loff = sB[tl] - cv;
    int node = (B0 << 8) + tl;
    if (node < N) row_off[node] = ebase + loff;
    if (B0 == 0 && tl == 0) row_off[N] = E;
    run[tl] = loff;
  }
  __syncthreads();
  // rank + scatter into csr (writes stay within this bucket's contiguous region)
  for (int i = tl; i < bsz; i += 512) {
    int w = bp[i];
    int r = atomicAdd(&run[w & 255], 1);
    csr[ebase + r] = w >> 8;
  }
}

// ---------------- layer-1 gather+mean into LDS tile (16 rows x 128, stride 136) ----
// DUAL-STREAM: each 16-lane group aggregates TWO nodes concurrently (independent
// acc chains, shared max-trip loop, unroll 8) -> up to 2x outstanding loads/lane.
// Guards are group-uniform (same node across the 16 lanes). Per-node edge order
// unchanged -> bit-identical to the single-stream form.
__device__ __forceinline__ void agg_to_lds(const _Float16* __restrict__ X,
                                           const int* __restrict__ row_off,
                                           const int* __restrict__ csr,
                                           _Float16* ab, int* eidx,
                                           int row0, int M, int lane) {
  int nd_end = min(row0 + 16, M);
  int ebeg = row_off[row0 < M ? row0 : M - 1];
  int eend = row_off[nd_end];
  int cnt  = eend - ebeg;
  bool fits = (cnt <= EC);
  if (fits)
    for (int i = lane; i < cnt; i += 64) eidx[i] = csr[ebeg + i];
  int g = lane >> 4, j = lane & 15;
#pragma unroll
  for (int pair = 0; pair < 2; ++pair) {
    int nodeA = row0 + pair * 8 + g;               // rows {g, g+4} then {g+8, g+12}
    int nodeB = nodeA + 4;
    int ncA = (nodeA < M) ? nodeA : M - 1;
    int ncB = (nodeB < M) ? nodeB : M - 1;
    int begA = row_off[ncA], endA = row_off[ncA + 1];
    int begB = row_off[ncB], endB = row_off[ncB + 1];
    int da = endA - begA, db = endB - begB;
    int dmax = da > db ? da : db;
    half8 accA = (half8)(_Float16)0.f, accB = (half8)(_Float16)0.f;
    if (fits) {
      const int* ixA = eidx + (begA - ebeg);
      const int* ixB = eidx + (begB - ebeg);
#pragma unroll 8
      for (int e = 0; e < dmax; ++e) {
        if (e < da) accA += *(const half8*)(X + (long)ixA[e] * 128 + j * 8);
        if (e < db) accB += *(const half8*)(X + (long)ixB[e] * 128 + j * 8);
      }
    } else {
#pragma unroll 8
      for (int e = 0; e < dmax; ++e) {
        if (e < da) accA += *(const half8*)(X + (long)csr[begA + e] * 128 + j * 8);
        if (e < db) accB += *(const half8*)(X + (long)csr[begB + e] * 128 + j * 8);
      }
    }
    accA *= (half8)(_Float16)(1.f / fmaxf((float)da, 1.f));
    accB *= (half8)(_Float16)(1.f / fmaxf((float)db, 1.f));
    *(half8*)(ab + (pair * 8 + g) * 136 + j * 8) = accA;
    *(half8*)(ab + (pair * 8 + g + 4) * 136 + j * 8) = accB;
  }
}

// ---------------- fused layer-1 + folded layer-2 GEMM ------------------------------
// Round-5 proven form (wave-private, NO intra-block barriers) + setprio on MFMAs.
__global__ __launch_bounds__(128) void gemm1z_k(const _Float16* __restrict__ X,
                                                const int* __restrict__ row_off,
                                                const int* __restrict__ csr,
                                                const _Float16* __restrict__ Bp,
                                                const float* __restrict__ bias,
                                                const _Float16* __restrict__ Bz,
                                                const float* __restrict__ bprime,
                                                _Float16* __restrict__ Zl,
                                                float* __restrict__ Pr, int M) {
  __shared__ _Float16 abuf[2][16 * 136];
  __shared__ int      ebuf[2][EC];
  int wave = threadIdx.x >> 6, lane = threadIdx.x & 63;
  _Float16* ab = abuf[wave];
  int row0 = blockIdx.x * 32 + wave * 16;
  agg_to_lds(X, row_off, csr, ab, ebuf[wave], row0, M, lane);
  int m = lane & 15, quad = lane >> 4;
  int arow = row0 + m; if (arow > M - 1) arow = M - 1;
  f32x4 acc[8];
#pragma unroll
  for (int i = 0; i < 8; ++i) acc[i] = (f32x4){0.f, 0.f, 0.f, 0.f};
#pragma unroll
  for (int kt = 0; kt < 8; ++kt) {
    half8 af = (kt < 4) ? *(const half8*)(ab + m * 136 + kt * 32 + quad * 8)
                        : *(const half8*)(X + (long)arow * 128 + (kt - 4) * 32 + quad * 8);
    __builtin_amdgcn_s_setprio(1);
#pragma unroll
    for (int nt = 0; nt < 8; ++nt) {
      half8 bf = *(const half8*)(Bp + ((long)(kt * 8 + nt) * 64 + lane) * 8);
      acc[nt] = __builtin_amdgcn_mfma_f32_16x16x32_f16(af, bf, acc[nt], 0, 0, 0);
    }
    __builtin_amdgcn_s_setprio(0);
  }
  // h1 tile: +b1, relu, stage into ab (agg contents dead; same f16 rounding as before)
#pragma unroll
  for (int nt = 0; nt < 8; ++nt) {
    float bv = bias[nt * 16 + m];
#pragma unroll
    for (int r = 0; r < 4; ++r)
      ab[(quad * 4 + r) * 136 + nt * 16 + m] = (_Float16)fmaxf(acc[nt][r] + bv, 0.f);
  }
  // folded layer-2: Zl = h1@W2lc, Pr = h1@W2rc + b'
  f32x4 a0 = (f32x4){0.f, 0.f, 0.f, 0.f}, a1 = a0;
  __builtin_amdgcn_s_setprio(1);
#pragma unroll
  for (int kt = 0; kt < 4; ++kt) {
    half8 af = *(const half8*)(ab + m * 136 + kt * 32 + quad * 8);
    half8 b0 = *(const half8*)(Bz + ((long)(kt * 2 + 0) * 64 + lane) * 8);
    half8 b1 = *(const half8*)(Bz + ((long)(kt * 2 + 1) * 64 + lane) * 8);
    a0 = __builtin_amdgcn_mfma_f32_16x16x32_f16(af, b0, a0, 0, 0, 0);
    a1 = __builtin_amdgcn_mfma_f32_16x16x32_f16(af, b1, a1, 0, 0, 0);
  }
  __builtin_amdgcn_s_setprio(0);
  float bv = bprime[m];
#pragma unroll
  for (int r = 0; r < 4; ++r) {
    int orow = row0 + quad * 4 + r;
    if (orow < M) {
      Zl[(long)orow * 16 + m] = (_Float16)a0[r];
      Pr[(long)orow * 16 + m] = a1[r] + bv;
    }
  }
}

// ---------------- final: out = mean_agg(Zl) + Pr --------------------------------
// Round-2 proven form: 4 lanes/node, unroll-8 MLP edge loop.
__global__ __launch_bounds__(256) void aggout_k(const _Float16* __restrict__ Zl,
                                                const float* __restrict__ Pr,
                                                const int* __restrict__ row_off,
                                                const int* __restrict__ csr,
                                                float* __restrict__ out, int M) {
  int t = blockIdx.x * 256 + threadIdx.x;
  int node = t >> 2, q = t & 3;
  if (node >= M) return;
  int beg = row_off[node], end = row_off[node + 1];
  float a0 = 0.f, a1 = 0.f, a2 = 0.f, a3 = 0.f;
#pragma unroll 8
  for (int e = beg; e < end; ++e) {
    half4 v = *(const half4*)(Zl + (long)csr[e] * 16 + q * 4);
    a0 += (float)v[0]; a1 += (float)v[1]; a2 += (float)v[2]; a3 += (float)v[3];
  }
  float inv = 1.f / fmaxf((float)(end - beg), 1.f);
  long o = (long)node * 16 + q * 4;
  const float4 pv = *(const float4*)(Pr + o);
  float4 ov;
  ov.x = a0 * inv + pv.x; ov.y = a1 * inv + pv.y;
  ov.z = a2 * inv + pv.z; ov.w = a3 * inv + pv.w;
  *(float4*)(out + o) = ov;
}

extern "C" void kernel_launch(void* const* d_in, const int* in_sizes, int n_in,
                              void* d_out, int out_size, void* d_ws, size_t ws_size,
                              hipStream_t stream) {
  const int N = in_sizes[0];
  const int E = in_sizes[1] / 2;
  const int*   entity = (const int*)d_in[0];
  const int*   e_src  = (const int*)d_in[1];
  const int*   e_dst  = e_src + E;
  const float* emb    = (const float*)d_in[2];
  const float* W1l    = (const float*)d_in[3];
  const float* b1     = (const float*)d_in[4];
  const float* W1r    = (const float*)d_in[5];
  const float* W2l    = (const float*)d_in[6];
  const float* b2     = (const float*)d_in[7];
  const float* W2r    = (const float*)d_in[8];
  const float* Wc     = (const float*)d_in[9];
  const float* bc     = (const float*)d_in[10];
  float* out = (float*)d_out;

  const int NBUCK = (N + 255) >> 8;        // 196 buckets of 256 nodes

  // workspace layout
  char* p = (char*)d_ws;
  _Float16* x0  = (_Float16*)p; p += (size_t)N * 128 * 2;
  _Float16* Wp1 = (_Float16*)p; p += 256 * 128 * 2;
  _Float16* Wz  = (_Float16*)p; p += 128 * 32 * 2;
  float*    bpr = (float*)p;    p += 16 * 4;
  _Float16* Zl  = (_Float16*)p; p += (size_t)N * 16 * 2;
  float*    Pr  = (float*)p;    p += (size_t)N * 16 * 4;
  int* cur     = (int*)p; p += (size_t)NBUCK * CPAD * 4;   // line-padded counters
  int* row_off = (int*)p; p += (size_t)(N + 1) * 4;
  int* csr     = (int*)p; p += (size_t)E * 4;
  int* buck    = (int*)p; p += (size_t)NBUCK * CAP * 4;

  const int NA  = (E + CHUNK - 1) / CHUNK; // 293 pass-A edge blocks
  const int GB  = (N * 16 + 255) / 256;    // 3125 gather units total
  const int IBA = (GA_PER + 1) * NA;       // pass-A interleaved region (edge + 4 gathers)
  int G1 = NA * GA_PER; if (G1 > GB) G1 = GB;   // gather units consumed in pass A
  const int G2 = GB - G1;                  // remainder rides pass B (~1953)
  const int BG = (G2 + 1) / 2;             // 512-thread gather blocks in pass B

  hipMemsetAsync(cur, 0, (size_t)NBUCK * CPAD * 4, stream);

  // pass A: bucket scatter ∥ gather (just enough to shadow edges) ∥ weight packs
  bucketA_k<<<IBA + 33, 256, 0, stream>>>(e_src, e_dst, cur, buck,
                                          entity, emb, x0, W1l, W1r, Wp1,
                                          W2l, W2r, Wc, Wz, b2, bc, bpr,
                                          N, E, NA, NBUCK, IBA);
  // pass B: per-bucket degree+scan+rank (no X dependency) ∥ remaining emb gather
  bucketB_k<<<NBUCK + BG, 512, 0, stream>>>(cur, buck, row_off, csr,
                                            entity, emb, x0, G1, N, E, NBUCK);
  // fused: h1 = relu([mean_agg(x0)|x0]@Wp1+b1) -> Zl = h1@W2lc, Pr = h1@W2rc + b'
  gemm1z_k<<<(N + 31) / 32, 128, 0, stream>>>(x0, row_off, csr, Wp1, b1,
                                              Wz, bpr, Zl, Pr, N);
  // out = mean_agg(Zl) + Pr   (32 B/edge gather)
  aggout_k<<<(N * 4 + 255) / 256, 256, 0, stream>>>(Zl, Pr, row_off, csr, out, N);
}

// Round 9
// 162.383 us; speedup vs baseline: 1.0365x; 1.0365x over previous
//
#include <hip/hip_runtime.h>

typedef _Float16 half4  __attribute__((ext_vector_type(4)));
typedef _Float16 half8  __attribute__((ext_vector_type(8)));
typedef float    f32x4  __attribute__((ext_vector_type(4)));

#define EC 768      // per-wave LDS edge-index capacity (now per 8-row slice)
#define CAP 4096    // bucket capacity (edges); E/NBUCK ~ 3061, ~17 sigma margin
#define CHUNK 2048  // edges per pass-A block (8 per thread, int4-vectorized)
#define CPAD 16     // cur[] stride in ints: one counter per 64B line (atomic decontention)
#define GA_PER 4    // gather units per edge block in pass A (rest ride pass B)

// ---------------- emb gather role: one half8 chunk per (unit,lane) ----------------
__device__ __forceinline__ void gather_unit(const int* __restrict__ ent,
                                            const float* __restrict__ emb,
                                            _Float16* __restrict__ X,
                                            int unit, int lt, int N) {
  int t = unit * 256 + lt;
  if (t >= N * 16) return;
  int node = t >> 4, g = t & 15;
  const float4* s = (const float4*)(emb + (long)ent[node] * 128 + g * 8);
  float4 a = s[0], c = s[1];
  half8 o;
  o[0] = (_Float16)a.x; o[1] = (_Float16)a.y; o[2] = (_Float16)a.z; o[3] = (_Float16)a.w;
  o[4] = (_Float16)c.x; o[5] = (_Float16)c.y; o[6] = (_Float16)c.z; o[7] = (_Float16)c.w;
  *(half8*)(X + (long)t * 8) = o;
}

// B-frag order: lane holds B[kt*32+(lane>>4)*8+j][nt*16+(lane&15)], j=0..7.
__device__ __forceinline__ void pack_dev(const float* Wa, const float* Wb,
                                         _Float16* out, int NT, int ncols, int t) {
  int lane = t & 63, tile = t >> 6;
  int nt = tile % NT, kt = tile / NT;
  int n  = nt * 16 + (lane & 15);
  int kb = kt * 32 + (lane >> 4) * 8;
  half8 o;
#pragma unroll
  for (int j = 0; j < 8; ++j) {
    int k = kb + j;
    float w = (k < 128) ? Wa[k * ncols + n] : Wb[(k - 128) * ncols + n];
    o[j] = (_Float16)w;
  }
  *(half8*)(out + (long)t * 8) = o;
}

// ---------------- pass A: LDS-histogram bucket scatter ∥ partial gather ∥ packs ---
__global__ __launch_bounds__(256) void bucketA_k(
    const int* __restrict__ src, const int* __restrict__ dst,
    int* __restrict__ cur, int* __restrict__ buck,
    const int* __restrict__ ent, const float* __restrict__ emb, _Float16* __restrict__ X,
    const float* __restrict__ W1l, const float* __restrict__ W1r, _Float16* __restrict__ Wp1,
    const float* __restrict__ W2l, const float* __restrict__ W2r, const float* __restrict__ Wc,
    _Float16* __restrict__ Wz, const float* __restrict__ b2, const float* __restrict__ bc,
    float* __restrict__ bpr, int N, int E, int NA, int NBUCK, int IBA) {
  int b = blockIdx.x;
  if (b < IBA) {
    int grp = b / (GA_PER + 1), ph = b % (GA_PER + 1);
    if (ph != 0) { gather_unit(ent, emb, X, grp * GA_PER + ph - 1, threadIdx.x, N); return; }
    __shared__ int lbin[256], gbase[256];
    int tl = threadIdx.x;
    lbin[tl] = 0; __syncthreads();
    int e0 = grp * CHUNK;
    int pk[8], bn[8], lr[8];
    if (e0 + CHUNK <= E) {                         // full block: int4-vectorized
      const int4* dp = (const int4*)(dst + e0 + tl * 8);
      const int4* sp = (const int4*)(src + e0 + tl * 8);
      int4 d0 = dp[0], d1 = dp[1], s0 = sp[0], s1 = sp[1];
      int dv[8] = {d0.x, d0.y, d0.z, d0.w, d1.x, d1.y, d1.z, d1.w};
      int sv[8] = {s0.x, s0.y, s0.z, s0.w, s1.x, s1.y, s1.z, s1.w};
#pragma unroll
      for (int k = 0; k < 8; ++k) {
        bn[k] = dv[k] >> 8;
        pk[k] = (sv[k] << 8) | (dv[k] & 255);
        lr[k] = atomicAdd(&lbin[bn[k]], 1);
      }
    } else {                                       // tail block: scalar guarded
#pragma unroll
      for (int k = 0; k < 8; ++k) {
        int e = e0 + tl * 8 + k;
        bn[k] = -1;
        if (e < E) {
          int d = dst[e];
          bn[k] = d >> 8;
          pk[k] = (src[e] << 8) | (d & 255);
          lr[k] = atomicAdd(&lbin[bn[k]], 1);
        }
      }
    }
    __syncthreads();
    gbase[tl] = (tl < NBUCK && lbin[tl]) ? atomicAdd(&cur[tl * CPAD], lbin[tl]) : 0;
    __syncthreads();
#pragma unroll
    for (int k = 0; k < 8; ++k) {
      if (bn[k] >= 0) {
        int idx = gbase[bn[k]] + lr[k];
        if (idx < CAP) buck[(long)bn[k] * CAP + idx] = pk[k];
      }
    }
  } else if (b < IBA + 16) {                       // W1 concat pack (KT=8, NT=8)
    pack_dev(W1l, W1r, Wp1, 8, 128, (b - IBA) * 256 + threadIdx.x);
  } else if (b < IBA + 32) {                       // Wz fold: one elem/thread
    int i = (b - IBA - 16) * 256 + threadIdx.x;    // packed element index, 4096 total
    int j = i & 7, lane = (i >> 3) & 63, tile = i >> 9;
    int nt = tile & 1, kt = tile >> 1;
    int k = kt * 32 + (lane >> 4) * 8 + j;
    int c = lane & 15;
    const float* W = nt ? W2r : W2l;
    float s = 0.f;
#pragma unroll 8
    for (int q = 0; q < 128; ++q) s += W[k * 128 + q] * Wc[q * 16 + c];
    Wz[i] = (_Float16)s;
  } else {                                         // b' = b2@Wc + bc
    int n = threadIdx.x;
    if (n < 16) {
      float s = bc[n];
      for (int k = 0; k < 128; ++k) s += b2[k] * Wc[k * 16 + n];
      bpr[n] = s;
    }
  }
}

// ---------------- pass B: per-bucket degree+scan+rank ∥ remaining emb gather ------
__global__ __launch_bounds__(512) void bucketB_k(
    const int* __restrict__ cur, const int* __restrict__ buck,
    int* __restrict__ row_off, int* __restrict__ csr,
    const int* __restrict__ ent, const float* __restrict__ emb,
    _Float16* __restrict__ X, int goff, int N, int E, int NBUCK) {
  int B0 = blockIdx.x, tl = threadIdx.x;
  if (B0 >= NBUCK) {                               // gather role: 2 units per block
    int unit = goff + (B0 - NBUCK) * 2 + (tl >> 8);
    gather_unit(ent, emb, X, unit, tl & 255, N);
    return;
  }
  __shared__ int sA[256], cnt[256], sB[256], run[256];
  if (tl < 256) sA[tl] = (tl < NBUCK) ? cur[tl * CPAD] : 0;
  if (tl < 256) cnt[tl] = 0;
  __syncthreads();
  for (int off = 1; off < 256; off <<= 1) {
    int a = (tl < 256) ? sA[tl] : 0;
    int bb = (tl >= off && tl < 256) ? sA[tl - off] : 0;
    __syncthreads();
    if (tl < 256) sA[tl] = a + bb;
    __syncthreads();
  }
  int bsz = cur[B0 * CPAD]; if (bsz > CAP) bsz = CAP;
  int ebase = sA[B0] - bsz;
  const int* bp = buck + (long)B0 * CAP;
  for (int i = tl; i < bsz; i += 512) atomicAdd(&cnt[bp[i] & 255], 1);
  __syncthreads();
  int cv = (tl < 256) ? cnt[tl] : 0;
  if (tl < 256) sB[tl] = cv;
  __syncthreads();
  for (int off = 1; off < 256; off <<= 1) {
    int a = (tl < 256) ? sB[tl] : 0;
    int bb = (tl >= off && tl < 256) ? sB[tl - off] : 0;
    __syncthreads();
    if (tl < 256) sB[tl] = a + bb;
    __syncthreads();
  }
  if (tl < 256) {
    int loff = sB[tl] - cv;
    int node = (B0 << 8) + tl;
    if (node < N) row_off[node] = ebase + loff;
    if (B0 == 0 && tl == 0) row_off[N] = E;
    run[tl] = loff;
  }
  __syncthreads();
  for (int i = tl; i < bsz; i += 512) {
    int w = bp[i];
    int r = atomicAdd(&run[w & 255], 1);
    csr[ebase + r] = w >> 8;
  }
}

// ---------------- layer-1 gather+mean: 8 rows per wave into shared 32x136 tile ----
// Round-2 proven per-node loop (unroll-8 MLP), wave-private eidx, 2 batches.
__device__ __forceinline__ void agg8(const _Float16* __restrict__ X,
                                     const int* __restrict__ row_off,
                                     const int* __restrict__ csr,
                                     _Float16* ab,   // this wave's 8-row slice (stride 136)
                                     int* eidx,      // wave-private EC ints
                                     int rowbase, int M, int lane) {
  int rb0 = rowbase < M ? rowbase : M - 1;
  int rb1 = rowbase + 8; if (rb1 > M) rb1 = M;      // rb1 >= rb0+1 always
  int ebeg = row_off[rb0], eend = row_off[rb1];
  int cnt  = eend - ebeg;
  bool fits = (cnt <= EC);
  if (fits)
    for (int i = lane; i < cnt; i += 64) eidx[i] = csr[ebeg + i];
  int g = lane >> 4, j = lane & 15;
#pragma unroll
  for (int batch = 0; batch < 2; ++batch) {
    int node = rowbase + batch * 4 + g;
    int nc = (node < M) ? node : M - 1;
    int beg = row_off[nc], end = row_off[nc + 1];
    half8 acc = (half8)(_Float16)0.f;
    if (fits) {
      const int* ix = eidx + (beg - ebeg);
      int n = end - beg;
#pragma unroll 8
      for (int e = 0; e < n; ++e) {
        half8 v = *(const half8*)(X + (long)ix[e] * 128 + j * 8);
        acc += v;
      }
    } else {
#pragma unroll 8
      for (int e = beg; e < end; ++e) {
        half8 v = *(const half8*)(X + (long)csr[e] * 128 + j * 8);
        acc += v;
      }
    }
    _Float16 inv = (_Float16)(1.f / fmaxf((float)(end - beg), 1.f));
    acc *= (half8)inv;
    *(half8*)(ab + (batch * 4 + g) * 136 + j * 8) = acc;
  }
}

// ---------------- fused layer-1 + folded layer-2 GEMM (4-wave cooperative) --------
// 32 rows/block, 256 threads: wave w aggs rows [w*8, w*8+8) -> barrier ->
// wave w MFMAs row-tile (w>>1) x col-half (w&1) -> h1 into dead ebuf space ->
// barrier -> wave pair splits Zl (c==0) / Pr (c==1). Doubles waves/CU vs the
// 2-wave form (grid-limited occupancy 26% -> ~50%). Bit-identical math.
__global__ __launch_bounds__(256) void gemm1z_k(const _Float16* __restrict__ X,
                                                const int* __restrict__ row_off,
                                                const int* __restrict__ csr,
                                                const _Float16* __restrict__ Bp,
                                                const float* __restrict__ bias,
                                                const _Float16* __restrict__ Bz,
                                                const float* __restrict__ bprime,
                                                _Float16* __restrict__ Zl,
                                                float* __restrict__ Pr, int M) {
  __shared__ _Float16 abuf[32 * 136];              // agg tile (8704 B)
  __shared__ int      ebuf_raw[4 * EC];            // eidx; reused as h1 tile (12288 B)
  _Float16* h1b = (_Float16*)ebuf_raw;             // 32x136 f16 fits in 12288 B
  int wave = threadIdx.x >> 6, lane = threadIdx.x & 63;
  int row0 = blockIdx.x * 32;
  agg8(X, row_off, csr, abuf + wave * 8 * 136, ebuf_raw + wave * EC,
       row0 + wave * 8, M, lane);
  __syncthreads();                                 // agg tile complete; eidx dead
  int m = lane & 15, quad = lane >> 4;
  int r = wave >> 1, c = wave & 1;
  int mrow = r * 16 + m;
  int arow = row0 + mrow; if (arow > M - 1) arow = M - 1;
  f32x4 acc[4];
#pragma unroll
  for (int i = 0; i < 4; ++i) acc[i] = (f32x4){0.f, 0.f, 0.f, 0.f};
#pragma unroll
  for (int kt = 0; kt < 8; ++kt) {
    half8 af = (kt < 4) ? *(const half8*)(abuf + mrow * 136 + kt * 32 + quad * 8)
                        : *(const half8*)(X + (long)arow * 128 + (kt - 4) * 32 + quad * 8);
    __builtin_amdgcn_s_setprio(1);
#pragma unroll
    for (int nt = 0; nt < 4; ++nt) {
      half8 bf = *(const half8*)(Bp + ((long)(kt * 8 + c * 4 + nt) * 64 + lane) * 8);
      acc[nt] = __builtin_amdgcn_mfma_f32_16x16x32_f16(af, bf, acc[nt], 0, 0, 0);
    }
    __builtin_amdgcn_s_setprio(0);
  }
  // h1 quarter: +b1, relu -> h1b (ebuf space; safe: all eidx use ended at barrier 1)
#pragma unroll
  for (int nt = 0; nt < 4; ++nt) {
    float bv = bias[c * 64 + nt * 16 + m];
#pragma unroll
    for (int rr = 0; rr < 4; ++rr)
      h1b[(r * 16 + quad * 4 + rr) * 136 + c * 64 + nt * 16 + m] =
          (_Float16)fmaxf(acc[nt][rr] + bv, 0.f);
  }
  __syncthreads();                                 // full h1 tile visible
  // folded layer-2: c==0 -> Zl stream, c==1 -> Pr stream (same op order as before)
  f32x4 a0 = (f32x4){0.f, 0.f, 0.f, 0.f};
  __builtin_amdgcn_s_setprio(1);
#pragma unroll
  for (int kt = 0; kt < 4; ++kt) {
    half8 af = *(const half8*)(h1b + mrow * 136 + kt * 32 + quad * 8);
    half8 bf = *(const half8*)(Bz + ((long)(kt * 2 + c) * 64 + lane) * 8);
    a0 = __builtin_amdgcn_mfma_f32_16x16x32_f16(af, bf, a0, 0, 0, 0);
  }
  __builtin_amdgcn_s_setprio(0);
  float bv = bprime[m];
#pragma unroll
  for (int rr = 0; rr < 4; ++rr) {
    int orow = row0 + r * 16 + quad * 4 + rr;
    if (orow < M) {
      if (c == 0) Zl[(long)orow * 16 + m] = (_Float16)a0[rr];
      else        Pr[(long)orow * 16 + m] = a0[rr] + bv;
    }
  }
}

// ---------------- final: out = mean_agg(Zl) + Pr --------------------------------
// Round-2 proven form: 4 lanes/node, unroll-8 MLP edge loop.
__global__ __launch_bounds__(256) void aggout_k(const _Float16* __restrict__ Zl,
                                                const float* __restrict__ Pr,
                                                const int* __restrict__ row_off,
                                                const int* __restrict__ csr,
                                                float* __restrict__ out, int M) {
  int t = blockIdx.x * 256 + threadIdx.x;
  int node = t >> 2, q = t & 3;
  if (node >= M) return;
  int beg = row_off[node], end = row_off[node + 1];
  float a0 = 0.f, a1 = 0.f, a2 = 0.f, a3 = 0.f;
#pragma unroll 8
  for (int e = beg; e < end; ++e) {
    half4 v = *(const half4*)(Zl + (long)csr[e] * 16 + q * 4);
    a0 += (float)v[0]; a1 += (float)v[1]; a2 += (float)v[2]; a3 += (float)v[3];
  }
  float inv = 1.f / fmaxf((float)(end - beg), 1.f);
  long o = (long)node * 16 + q * 4;
  const float4 pv = *(const float4*)(Pr + o);
  float4 ov;
  ov.x = a0 * inv + pv.x; ov.y = a1 * inv + pv.y;
  ov.z = a2 * inv + pv.z; ov.w = a3 * inv + pv.w;
  *(float4*)(out + o) = ov;
}

extern "C" void kernel_launch(void* const* d_in, const int* in_sizes, int n_in,
                              void* d_out, int out_size, void* d_ws, size_t ws_size,
                              hipStream_t stream) {
  const int N = in_sizes[0];
  const int E = in_sizes[1] / 2;
  const int*   entity = (const int*)d_in[0];
  const int*   e_src  = (const int*)d_in[1];
  const int*   e_dst  = e_src + E;
  const float* emb    = (const float*)d_in[2];
  const float* W1l    = (const float*)d_in[3];
  const float* b1     = (const float*)d_in[4];
  const float* W1r    = (const float*)d_in[5];
  const float* W2l    = (const float*)d_in[6];
  const float* b2     = (const float*)d_in[7];
  const float* W2r    = (const float*)d_in[8];
  const float* Wc     = (const float*)d_in[9];
  const float* bc     = (const float*)d_in[10];
  float* out = (float*)d_out;

  const int NBUCK = (N + 255) >> 8;        // 196 buckets of 256 nodes

  // workspace layout
  char* p = (char*)d_ws;
  _Float16* x0  = (_Float16*)p; p += (size_t)N * 128 * 2;
  _Float16* Wp1 = (_Float16*)p; p += 256 * 128 * 2;
  _Float16* Wz  = (_Float16*)p; p += 128 * 32 * 2;
  float*    bpr = (float*)p;    p += 16 * 4;
  _Float16* Zl  = (_Float16*)p; p += (size_t)N * 16 * 2;
  float*    Pr  = (float*)p;    p += (size_t)N * 16 * 4;
  int* cur     = (int*)p; p += (size_t)NBUCK * CPAD * 4;   // line-padded counters
  int* row_off = (int*)p; p += (size_t)(N + 1) * 4;
  int* csr     = (int*)p; p += (size_t)E * 4;
  int* buck    = (int*)p; p += (size_t)NBUCK * CAP * 4;

  const int NA  = (E + CHUNK - 1) / CHUNK; // 293 pass-A edge blocks
  const int GB  = (N * 16 + 255) / 256;    // 3125 gather units total
  const int IBA = (GA_PER + 1) * NA;       // pass-A interleaved region (edge + 4 gathers)
  int G1 = NA * GA_PER; if (G1 > GB) G1 = GB;   // gather units consumed in pass A
  const int G2 = GB - G1;                  // remainder rides pass B (~1953)
  const int BG = (G2 + 1) / 2;             // 512-thread gather blocks in pass B

  hipMemsetAsync(cur, 0, (size_t)NBUCK * CPAD * 4, stream);

  // pass A: bucket scatter ∥ gather (just enough to shadow edges) ∥ weight packs
  bucketA_k<<<IBA + 33, 256, 0, stream>>>(e_src, e_dst, cur, buck,
                                          entity, emb, x0, W1l, W1r, Wp1,
                                          W2l, W2r, Wc, Wz, b2, bc, bpr,
                                          N, E, NA, NBUCK, IBA);
  // pass B: per-bucket degree+scan+rank (no X dependency) ∥ remaining emb gather
  bucketB_k<<<NBUCK + BG, 512, 0, stream>>>(cur, buck, row_off, csr,
                                            entity, emb, x0, G1, N, E, NBUCK);
  // fused: h1 = relu([mean_agg(x0)|x0]@Wp1+b1) -> Zl = h1@W2lc, Pr = h1@W2rc + b'
  gemm1z_k<<<(N + 31) / 32, 256, 0, stream>>>(x0, row_off, csr, Wp1, b1,
                                              Wz, bpr, Zl, Pr, N);
  // out = mean_agg(Zl) + Pr   (32 B/edge gather)
  aggout_k<<<(N * 4 + 255) / 256, 256, 0, stream>>>(Zl, Pr, row_off, csr, out, N);
}

// Round 10
// 155.557 us; speedup vs baseline: 1.0820x; 1.0439x over previous
//
#include <hip/hip_runtime.h>

typedef _Float16 half4  __attribute__((ext_vector_type(4)));
typedef _Float16 half8  __attribute__((ext_vector_type(8)));
typedef float    f32x4  __attribute__((ext_vector_type(4)));

#define EC 768      // per-wave LDS edge-index capacity for layer-1 chain-break
#define CAP 4096    // bucket capacity (edges); E/NBUCK ~ 3061, ~17 sigma margin
#define CHUNK 2048  // edges per pass-A block (8 per thread, int4-vectorized)
#define CPAD 16     // cur[] stride in ints: one counter per 64B line (atomic decontention)
#define GA_PER 4    // gather units per edge block in pass A (rest ride pass B)

// ---------------- emb gather role: one half8 chunk per (unit,lane) ----------------
__device__ __forceinline__ void gather_unit(const int* __restrict__ ent,
                                            const float* __restrict__ emb,
                                            _Float16* __restrict__ X,
                                            int unit, int lt, int N) {
  int t = unit * 256 + lt;
  if (t >= N * 16) return;
  int node = t >> 4, g = t & 15;
  const float4* s = (const float4*)(emb + (long)ent[node] * 128 + g * 8);
  float4 a = s[0], c = s[1];
  half8 o;
  o[0] = (_Float16)a.x; o[1] = (_Float16)a.y; o[2] = (_Float16)a.z; o[3] = (_Float16)a.w;
  o[4] = (_Float16)c.x; o[5] = (_Float16)c.y; o[6] = (_Float16)c.z; o[7] = (_Float16)c.w;
  *(half8*)(X + (long)t * 8) = o;
}

// B-frag order: lane holds B[kt*32+(lane>>4)*8+j][nt*16+(lane&15)], j=0..7.
__device__ __forceinline__ void pack_dev(const float* Wa, const float* Wb,
                                         _Float16* out, int NT, int ncols, int t) {
  int lane = t & 63, tile = t >> 6;
  int nt = tile % NT, kt = tile / NT;
  int n  = nt * 16 + (lane & 15);
  int kb = kt * 32 + (lane >> 4) * 8;
  half8 o;
#pragma unroll
  for (int j = 0; j < 8; ++j) {
    int k = kb + j;
    float w = (k < 128) ? Wa[k * ncols + n] : Wb[(k - 128) * ncols + n];
    o[j] = (_Float16)w;
  }
  *(half8*)(out + (long)t * 8) = o;
}

// ---------------- pass A: LDS-histogram bucket scatter ∥ partial gather ∥ packs ---
// Edges binned by dst>>8 into fixed CAP regions. Per (block,bin) ONE global atomic
// (space allocation, line-padded counters); per-edge rank from LDS histogram return.
// Packed word: (src<<8)|(dst&255) — 4 B/edge (requires N < 2^23).
__global__ __launch_bounds__(256) void bucketA_k(
    const int* __restrict__ src, const int* __restrict__ dst,
    int* __restrict__ cur, int* __restrict__ buck,
    const int* __restrict__ ent, const float* __restrict__ emb, _Float16* __restrict__ X,
    const float* __restrict__ W1l, const float* __restrict__ W1r, _Float16* __restrict__ Wp1,
    const float* __restrict__ W2l, const float* __restrict__ W2r, const float* __restrict__ Wc,
    _Float16* __restrict__ Wz, const float* __restrict__ b2, const float* __restrict__ bc,
    float* __restrict__ bpr, int N, int E, int NA, int NBUCK, int IBA) {
  int b = blockIdx.x;
  if (b < IBA) {
    int grp = b / (GA_PER + 1), ph = b % (GA_PER + 1);
    if (ph != 0) { gather_unit(ent, emb, X, grp * GA_PER + ph - 1, threadIdx.x, N); return; }
    __shared__ int lbin[256], gbase[256];
    int tl = threadIdx.x;
    lbin[tl] = 0; __syncthreads();
    int e0 = grp * CHUNK;
    int pk[8], bn[8], lr[8];
    if (e0 + CHUNK <= E) {                         // full block: int4-vectorized
      const int4* dp = (const int4*)(dst + e0 + tl * 8);
      const int4* sp = (const int4*)(src + e0 + tl * 8);
      int4 d0 = dp[0], d1 = dp[1], s0 = sp[0], s1 = sp[1];
      int dv[8] = {d0.x, d0.y, d0.z, d0.w, d1.x, d1.y, d1.z, d1.w};
      int sv[8] = {s0.x, s0.y, s0.z, s0.w, s1.x, s1.y, s1.z, s1.w};
#pragma unroll
      for (int k = 0; k < 8; ++k) {
        bn[k] = dv[k] >> 8;
        pk[k] = (sv[k] << 8) | (dv[k] & 255);
        lr[k] = atomicAdd(&lbin[bn[k]], 1);
      }
    } else {                                       // tail block: scalar guarded
#pragma unroll
      for (int k = 0; k < 8; ++k) {
        int e = e0 + tl * 8 + k;
        bn[k] = -1;
        if (e < E) {
          int d = dst[e];
          bn[k] = d >> 8;
          pk[k] = (src[e] << 8) | (d & 255);
          lr[k] = atomicAdd(&lbin[bn[k]], 1);
        }
      }
    }
    __syncthreads();
    gbase[tl] = (tl < NBUCK && lbin[tl]) ? atomicAdd(&cur[tl * CPAD], lbin[tl]) : 0;
    __syncthreads();
#pragma unroll
    for (int k = 0; k < 8; ++k) {
      if (bn[k] >= 0) {
        int idx = gbase[bn[k]] + lr[k];
        if (idx < CAP) buck[(long)bn[k] * CAP + idx] = pk[k];
      }
    }
  } else if (b < IBA + 16) {                       // W1 concat pack (KT=8, NT=8)
    pack_dev(W1l, W1r, Wp1, 8, 128, (b - IBA) * 256 + threadIdx.x);
  } else if (b < IBA + 32) {                       // Wz fold: one elem/thread
    int i = (b - IBA - 16) * 256 + threadIdx.x;    // packed element index, 4096 total
    int j = i & 7, lane = (i >> 3) & 63, tile = i >> 9;
    int nt = tile & 1, kt = tile >> 1;
    int k = kt * 32 + (lane >> 4) * 8 + j;
    int c = lane & 15;
    const float* W = nt ? W2r : W2l;
    float s = 0.f;
#pragma unroll 8
    for (int q = 0; q < 128; ++q) s += W[k * 128 + q] * Wc[q * 16 + c];
    Wz[i] = (_Float16)s;
  } else {                                         // b' = b2@Wc + bc
    int n = threadIdx.x;
    if (n < 16) {
      float s = bc[n];
      for (int k = 0; k < 128; ++k) s += b2[k] * Wc[k * 16 + n];
      bpr[n] = s;
    }
  }
}

// ---------------- pass B: per-bucket degree+scan+rank ∥ remaining emb gather ------
// One 512-thread block per bucket (256 nodes); gather-ballast blocks (2 units each)
// fill the machine. bucketB needs only buck/cur — no X dependency.
__global__ __launch_bounds__(512) void bucketB_k(
    const int* __restrict__ cur, const int* __restrict__ buck,
    int* __restrict__ row_off, int* __restrict__ csr,
    const int* __restrict__ ent, const float* __restrict__ emb,
    _Float16* __restrict__ X, int goff, int N, int E, int NBUCK) {
  int B0 = blockIdx.x, tl = threadIdx.x;
  if (B0 >= NBUCK) {                               // gather role: 2 units per block
    int unit = goff + (B0 - NBUCK) * 2 + (tl >> 8);
    gather_unit(ent, emb, X, unit, tl & 255, N);
    return;
  }
  __shared__ int sA[256], cnt[256], sB[256], run[256];
  // exclusive prefix of bucket sizes -> this bucket's global edge base
  if (tl < 256) sA[tl] = (tl < NBUCK) ? cur[tl * CPAD] : 0;
  if (tl < 256) cnt[tl] = 0;
  __syncthreads();
  for (int off = 1; off < 256; off <<= 1) {
    int a = (tl < 256) ? sA[tl] : 0;
    int bb = (tl >= off && tl < 256) ? sA[tl - off] : 0;
    __syncthreads();
    if (tl < 256) sA[tl] = a + bb;
    __syncthreads();
  }
  int bsz = cur[B0 * CPAD]; if (bsz > CAP) bsz = CAP;
  int ebase = sA[B0] - bsz;
  // per-node counts (LDS atomics)
  const int* bp = buck + (long)B0 * CAP;
  for (int i = tl; i < bsz; i += 512) atomicAdd(&cnt[bp[i] & 255], 1);
  __syncthreads();
  // exclusive scan -> local row offsets
  int cv = (tl < 256) ? cnt[tl] : 0;
  if (tl < 256) sB[tl] = cv;
  __syncthreads();
  for (int off = 1; off < 256; off <<= 1) {
    int a = (tl < 256) ? sB[tl] : 0;
    int bb = (tl >= off && tl < 256) ? sB[tl - off] : 0;
    __syncthreads();
    if (tl < 256) sB[tl] = a + bb;
    __syncthreads();
  }
  if (tl < 256) {
    int loff = sB[tl] - cv;
    int node = (B0 << 8) + tl;
    if (node < N) row_off[node] = ebase + loff;
    if (B0 == 0 && tl == 0) row_off[N] = E;
    run[tl] = loff;
  }
  __syncthreads();
  // rank + scatter into csr (writes stay within this bucket's contiguous region)
  for (int i = tl; i < bsz; i += 512) {
    int w = bp[i];
    int r = atomicAdd(&run[w & 255], 1);
    csr[ebase + r] = w >> 8;
  }
}

// ---------------- layer-1 gather+mean into LDS tile (16 rows x 128, stride 136) ----
// Round-2 proven form: 4 node-groups x 16 col-lanes, unroll-8 MLP on the edge loop.
__device__ __forceinline__ void agg_to_lds(const _Float16* __restrict__ X,
                                           const int* __restrict__ row_off,
                                           const int* __restrict__ csr,
                                           _Float16* ab, int* eidx,
                                           int row0, int M, int lane) {
  int nd_end = min(row0 + 16, M);
  int ebeg = row_off[row0 < M ? row0 : M - 1];
  int eend = row_off[nd_end];
  int cnt  = eend - ebeg;
  bool fits = (cnt <= EC);
  if (fits)
    for (int i = lane; i < cnt; i += 64) eidx[i] = csr[ebeg + i];
  int g = lane >> 4, j = lane & 15;
#pragma unroll
  for (int batch = 0; batch < 4; ++batch) {
    int node = row0 + batch * 4 + g;
    int nc = (node < M) ? node : M - 1;
    int beg = row_off[nc], end = row_off[nc + 1];
    half8 acc = (half8)(_Float16)0.f;
    if (fits) {
      const int* ix = eidx + (beg - ebeg);
      int n = end - beg;
#pragma unroll 8
      for (int e = 0; e < n; ++e) {
        half8 v = *(const half8*)(X + (long)ix[e] * 128 + j * 8);
        acc += v;
      }
    } else {
#pragma unroll 8
      for (int e = beg; e < end; ++e) {
        half8 v = *(const half8*)(X + (long)csr[e] * 128 + j * 8);
        acc += v;
      }
    }
    _Float16 inv = (_Float16)(1.f / fmaxf((float)(end - beg), 1.f));
    acc *= (half8)inv;
    *(half8*)(ab + (batch * 4 + g) * 136 + j * 8) = acc;
  }
}

// ---------------- fused layer-1 + folded layer-2 GEMM ------------------------------
// Verified champion form (round 5, 155.8 µs): wave-private, no intra-block barriers.
__global__ __launch_bounds__(128) void gemm1z_k(const _Float16* __restrict__ X,
                                                const int* __restrict__ row_off,
                                                const int* __restrict__ csr,
                                                const _Float16* __restrict__ Bp,
                                                const float* __restrict__ bias,
                                                const _Float16* __restrict__ Bz,
                                                const float* __restrict__ bprime,
                                                _Float16* __restrict__ Zl,
                                                float* __restrict__ Pr, int M) {
  __shared__ _Float16 abuf[2][16 * 136];
  __shared__ int      ebuf[2][EC];
  int wave = threadIdx.x >> 6, lane = threadIdx.x & 63;
  _Float16* ab = abuf[wave];
  int row0 = blockIdx.x * 32 + wave * 16;
  agg_to_lds(X, row_off, csr, ab, ebuf[wave], row0, M, lane);
  int m = lane & 15, quad = lane >> 4;
  int arow = row0 + m; if (arow > M - 1) arow = M - 1;
  f32x4 acc[8];
#pragma unroll
  for (int i = 0; i < 8; ++i) acc[i] = (f32x4){0.f, 0.f, 0.f, 0.f};
#pragma unroll
  for (int kt = 0; kt < 8; ++kt) {
    half8 af = (kt < 4) ? *(const half8*)(ab + m * 136 + kt * 32 + quad * 8)
                        : *(const half8*)(X + (long)arow * 128 + (kt - 4) * 32 + quad * 8);
#pragma unroll
    for (int nt = 0; nt < 8; ++nt) {
      half8 bf = *(const half8*)(Bp + ((long)(kt * 8 + nt) * 64 + lane) * 8);
      acc[nt] = __builtin_amdgcn_mfma_f32_16x16x32_f16(af, bf, acc[nt], 0, 0, 0);
    }
  }
  // h1 tile: +b1, relu, stage into ab (agg contents dead; same f16 rounding as before)
#pragma unroll
  for (int nt = 0; nt < 8; ++nt) {
    float bv = bias[nt * 16 + m];
#pragma unroll
    for (int r = 0; r < 4; ++r)
      ab[(quad * 4 + r) * 136 + nt * 16 + m] = (_Float16)fmaxf(acc[nt][r] + bv, 0.f);
  }
  // folded layer-2: Zl = h1@W2lc, Pr = h1@W2rc + b'
  f32x4 a0 = (f32x4){0.f, 0.f, 0.f, 0.f}, a1 = a0;
#pragma unroll
  for (int kt = 0; kt < 4; ++kt) {
    half8 af = *(const half8*)(ab + m * 136 + kt * 32 + quad * 8);
    half8 b0 = *(const half8*)(Bz + ((long)(kt * 2 + 0) * 64 + lane) * 8);
    half8 b1 = *(const half8*)(Bz + ((long)(kt * 2 + 1) * 64 + lane) * 8);
    a0 = __builtin_amdgcn_mfma_f32_16x16x32_f16(af, b0, a0, 0, 0, 0);
    a1 = __builtin_amdgcn_mfma_f32_16x16x32_f16(af, b1, a1, 0, 0, 0);
  }
  float bv = bprime[m];
#pragma unroll
  for (int r = 0; r < 4; ++r) {
    int orow = row0 + quad * 4 + r;
    if (orow < M) {
      Zl[(long)orow * 16 + m] = (_Float16)a0[r];
      Pr[(long)orow * 16 + m] = a1[r] + bv;
    }
  }
}

// ---------------- final: out = mean_agg(Zl) + Pr --------------------------------
// Round-2 proven form: 4 lanes/node, unroll-8 MLP edge loop.
__global__ __launch_bounds__(256) void aggout_k(const _Float16* __restrict__ Zl,
                                                const float* __restrict__ Pr,
                                                const int* __restrict__ row_off,
                                                const int* __restrict__ csr,
                                                float* __restrict__ out, int M) {
  int t = blockIdx.x * 256 + threadIdx.x;
  int node = t >> 2, q = t & 3;
  if (node >= M) return;
  int beg = row_off[node], end = row_off[node + 1];
  float a0 = 0.f, a1 = 0.f, a2 = 0.f, a3 = 0.f;
#pragma unroll 8
  for (int e = beg; e < end; ++e) {
    half4 v = *(const half4*)(Zl + (long)csr[e] * 16 + q * 4);
    a0 += (float)v[0]; a1 += (float)v[1]; a2 += (float)v[2]; a3 += (float)v[3];
  }
  float inv = 1.f / fmaxf((float)(end - beg), 1.f);
  long o = (long)node * 16 + q * 4;
  const float4 pv = *(const float4*)(Pr + o);
  float4 ov;
  ov.x = a0 * inv + pv.x; ov.y = a1 * inv + pv.y;
  ov.z = a2 * inv + pv.z; ov.w = a3 * inv + pv.w;
  *(float4*)(out + o) = ov;
}

extern "C" void kernel_launch(void* const* d_in, const int* in_sizes, int n_in,
                              void* d_out, int out_size, void* d_ws, size_t ws_size,
                              hipStream_t stream) {
  const int N = in_sizes[0];
  const int E = in_sizes[1] / 2;
  const int*   entity = (const int*)d_in[0];
  const int*   e_src  = (const int*)d_in[1];
  const int*   e_dst  = e_src + E;
  const float* emb    = (const float*)d_in[2];
  const float* W1l    = (const float*)d_in[3];
  const float* b1     = (const float*)d_in[4];
  const float* W1r    = (const float*)d_in[5];
  const float* W2l    = (const float*)d_in[6];
  const float* b2     = (const float*)d_in[7];
  const float* W2r    = (const float*)d_in[8];
  const float* Wc     = (const float*)d_in[9];
  const float* bc     = (const float*)d_in[10];
  float* out = (float*)d_out;

  const int NBUCK = (N + 255) >> 8;        // 196 buckets of 256 nodes

  // workspace layout
  char* p = (char*)d_ws;
  _Float16* x0  = (_Float16*)p; p += (size_t)N * 128 * 2;
  _Float16* Wp1 = (_Float16*)p; p += 256 * 128 * 2;
  _Float16* Wz  = (_Float16*)p; p += 128 * 32 * 2;
  float*    bpr = (float*)p;    p += 16 * 4;
  _Float16* Zl  = (_Float16*)p; p += (size_t)N * 16 * 2;
  float*    Pr  = (float*)p;    p += (size_t)N * 16 * 4;
  int* cur     = (int*)p; p += (size_t)NBUCK * CPAD * 4;   // line-padded counters
  int* row_off = (int*)p; p += (size_t)(N + 1) * 4;
  int* csr     = (int*)p; p += (size_t)E * 4;
  int* buck    = (int*)p; p += (size_t)NBUCK * CAP * 4;

  const int NA  = (E + CHUNK - 1) / CHUNK; // 293 pass-A edge blocks
  const int GB  = (N * 16 + 255) / 256;    // 3125 gather units total
  const int IBA = (GA_PER + 1) * NA;       // pass-A interleaved region (edge + 4 gathers)
  int G1 = NA * GA_PER; if (G1 > GB) G1 = GB;   // gather units consumed in pass A
  const int G2 = GB - G1;                  // remainder rides pass B (~1953)
  const int BG = (G2 + 1) / 2;             // 512-thread gather blocks in pass B

  hipMemsetAsync(cur, 0, (size_t)NBUCK * CPAD * 4, stream);

  // pass A: bucket scatter ∥ gather (just enough to shadow edges) ∥ weight packs
  bucketA_k<<<IBA + 33, 256, 0, stream>>>(e_src, e_dst, cur, buck,
                                          entity, emb, x0, W1l, W1r, Wp1,
                                          W2l, W2r, Wc, Wz, b2, bc, bpr,
                                          N, E, NA, NBUCK, IBA);
  // pass B: per-bucket degree+scan+rank (no X dependency) ∥ remaining emb gather
  bucketB_k<<<NBUCK + BG, 512, 0, stream>>>(cur, buck, row_off, csr,
                                            entity, emb, x0, G1, N, E, NBUCK);
  // fused: h1 = relu([mean_agg(x0)|x0]@Wp1+b1) -> Zl = h1@W2lc, Pr = h1@W2rc + b'
  gemm1z_k<<<(N + 31) / 32, 128, 0, stream>>>(x0, row_off, csr, Wp1, b1,
                                              Wz, bpr, Zl, Pr, N);
  // out = mean_agg(Zl) + Pr   (32 B/edge gather)
  aggout_k<<<(N * 4 + 255) / 256, 256, 0, stream>>>(Zl, Pr, row_off, csr, out, N);
}